// Round 3
// baseline (2315.586 us; speedup 1.0000x reference)
//
#include <hip/hip_runtime.h>
#include <hip/hip_bf16.h>
#include <math.h>

// DualMAR: 2-layer weighted GCN (segment_sum message passing) over 100K nodes /
// 3.2M edges, code->visit->patient attention, 3-layer MLP decoder.
// Strategy: build CSR-by-dst on device (histogram + scan + fill), per-wave
// gather-sum agg (no f32 atomics), fp32 tiled GEMMs, per-node precompute of
// the code-attention score t[n] = tanh(emb[n]@Wv)@uv.

#define D 256            // D_IN = D_HID = D_OUT
#define BPAT 64          // B
#define VIS 50           // V
#define CODES 64         // C
#define NEG_INF -1e9f

// ---------------- CSR build ----------------

__global__ void hist_kernel(const int* __restrict__ ei, int* __restrict__ counts, int ne) {
    int e = blockIdx.x * blockDim.x + threadIdx.x;
    if (e < ne) atomicAdd(&counts[ei[(size_t)ne + e]], 1);
}

// Single-block exclusive scan: rp[i+1] = inclusive sum, rp[0]=0.
// Also rewrites counts[i] in place with the EXCLUSIVE prefix (fill cursor).
__global__ __launch_bounds__(1024) void scan_kernel(int* __restrict__ counts,
                                                    int* __restrict__ rp, int n) {
    __shared__ int s_wsum[16];
    __shared__ int s_carry;
    int tid = threadIdx.x;
    int lane = tid & 63, wid = tid >> 6;
    if (tid == 0) s_carry = 0;
    __syncthreads();
    for (int base = 0; base < n; base += 1024) {
        int i = base + tid;
        int v = (i < n) ? counts[i] : 0;
        int x = v;
        #pragma unroll
        for (int d = 1; d < 64; d <<= 1) {
            int y = __shfl_up(x, (unsigned)d, 64);
            if (lane >= d) x += y;
        }
        if (lane == 63) s_wsum[wid] = x;
        __syncthreads();
        int woff = 0;
        #pragma unroll
        for (int w = 0; w < 16; ++w) woff += (w < wid) ? s_wsum[w] : 0;
        int carry = s_carry;
        int incl = carry + woff + x;
        if (i < n) {
            rp[i + 1] = incl;
            counts[i] = incl - v;   // exclusive prefix = fill cursor
        }
        __syncthreads();
        if (tid == 1023) s_carry = incl;
        __syncthreads();
    }
    if (tid == 0) rp[0] = 0;
}

__global__ void fill_kernel(const int* __restrict__ ei, const float* __restrict__ ew,
                            int* __restrict__ cursor, int* __restrict__ csrc,
                            float* __restrict__ cw, int ne) {
    int e = blockIdx.x * blockDim.x + threadIdx.x;
    if (e >= ne) return;
    int d = ei[(size_t)ne + e];
    int pos = atomicAdd(&cursor[d], 1);
    csrc[pos] = ei[e];
    cw[pos] = ew[e];
}

// ---------------- weighted aggregation: out[i] = sum_{e: dst=i} w_e * x[src_e] ----------------
// One wave per dst row; each edge read = 64 lanes x float4 = coalesced 1KB row.
__global__ __launch_bounds__(256) void agg_kernel(
    const float* __restrict__ x, const int* __restrict__ rp,
    const int* __restrict__ csrc, const float* __restrict__ cw,
    float* __restrict__ out, int n) {
    int w = (int)(((size_t)blockIdx.x * blockDim.x + threadIdx.x) >> 6);
    int lane = threadIdx.x & 63;
    if (w >= n) return;
    int beg = rp[w], end = rp[w + 1];
    float ax = 0.f, ay = 0.f, az = 0.f, aw = 0.f;
    int e = beg;
    for (; e + 2 <= end; e += 2) {
        int s0 = csrc[e], s1 = csrc[e + 1];
        float w0 = cw[e], w1 = cw[e + 1];
        float4 v0 = ((const float4*)(x + (size_t)s0 * D))[lane];
        float4 v1 = ((const float4*)(x + (size_t)s1 * D))[lane];
        ax += w0 * v0.x + w1 * v1.x;
        ay += w0 * v0.y + w1 * v1.y;
        az += w0 * v0.z + w1 * v1.z;
        aw += w0 * v0.w + w1 * v1.w;
    }
    if (e < end) {
        int s0 = csrc[e];
        float w0 = cw[e];
        float4 v0 = ((const float4*)(x + (size_t)s0 * D))[lane];
        ax += w0 * v0.x; ay += w0 * v0.y; az += w0 * v0.z; aw += w0 * v0.w;
    }
    ((float4*)(out + (size_t)w * D))[lane] = make_float4(ax, ay, az, aw);
}

// ---------------- tiled fp32 GEMM: C = act(A[MxK] @ W[KxN] + bias) ----------------
// 64x64 tile, 256 threads, 4x4 micro-tile. act: 0=none, 1=relu, 2=tanh.
__global__ __launch_bounds__(256) void gemm_bias_act(
    const float* __restrict__ A, const float* __restrict__ W,
    const float* __restrict__ bias, float* __restrict__ C,
    int M, int N, int K, int act) {
    __shared__ float As[64][17];
    __shared__ float Bs[16][65];
    int tid = threadIdx.x;
    int brow = blockIdx.x * 64;
    int bcol = blockIdx.y * 64;
    int tr = tid >> 4;   // 0..15
    int tc = tid & 15;   // 0..15
    float acc[4][4] = {};
    for (int k0 = 0; k0 < K; k0 += 16) {
        {   // A tile 64x16: thread t -> row t/4, float4 at col (t%4)*4
            int r = tid >> 2;
            int c = (tid & 3) << 2;
            int gr = brow + r;
            float4 v = make_float4(0.f, 0.f, 0.f, 0.f);
            if (gr < M) v = *(const float4*)(A + (size_t)gr * K + k0 + c);
            As[r][c] = v.x; As[r][c + 1] = v.y; As[r][c + 2] = v.z; As[r][c + 3] = v.w;
        }
        {   // B tile 16x64: thread t -> row t/16, float4 at col (t%16)*4
            int r = tid >> 4;
            int c = (tid & 15) << 2;
            float4 v = *(const float4*)(W + (size_t)(k0 + r) * N + bcol + c);
            Bs[r][c] = v.x; Bs[r][c + 1] = v.y; Bs[r][c + 2] = v.z; Bs[r][c + 3] = v.w;
        }
        __syncthreads();
        #pragma unroll
        for (int kk = 0; kk < 16; ++kk) {
            float a[4], b[4];
            #pragma unroll
            for (int i = 0; i < 4; ++i) a[i] = As[tr * 4 + i][kk];
            #pragma unroll
            for (int j = 0; j < 4; ++j) b[j] = Bs[kk][tc * 4 + j];
            #pragma unroll
            for (int i = 0; i < 4; ++i)
                #pragma unroll
                for (int j = 0; j < 4; ++j)
                    acc[i][j] = fmaf(a[i], b[j], acc[i][j]);
        }
        __syncthreads();
    }
    #pragma unroll
    for (int i = 0; i < 4; ++i) {
        int gr = brow + tr * 4 + i;
        if (gr >= M) continue;
        #pragma unroll
        for (int j = 0; j < 4; ++j) {
            int gc = bcol + tc * 4 + j;
            float v = acc[i][j] + (bias ? bias[gc] : 0.f);
            if (act == 1) v = fmaxf(v, 0.f);
            else if (act == 2) v = tanhf(v);
            C[(size_t)gr * N + gc] = v;
        }
    }
}

// t[n] = dot(tanhmat[n,:], uv) — one wave per row
__global__ __launch_bounds__(256) void dot_uv_kernel(
    const float* __restrict__ tanhmat, const float* __restrict__ uv,
    float* __restrict__ t, int n) {
    int w = (int)(((size_t)blockIdx.x * blockDim.x + threadIdx.x) >> 6);
    int lane = threadIdx.x & 63;
    if (w >= n) return;
    float4 v = ((const float4*)(tanhmat + (size_t)w * D))[lane];
    float4 u = ((const float4*)uv)[lane];
    float s = v.x * u.x + v.y * u.y + v.z * u.z + v.w * u.w;
    #pragma unroll
    for (int d = 32; d; d >>= 1) s += __shfl_xor(s, d, 64);
    if (lane == 0) t[w] = s;
}

// ---------------- code attention: one block per (b,v) ----------------
__global__ __launch_bounds__(256) void code_attn_kernel(
    const int* __restrict__ codes, const float* __restrict__ t,
    const float* __restrict__ emb, float* __restrict__ vemb,
    int* __restrict__ vmask) {
    int bv = blockIdx.x;
    int tid = threadIdx.x;
    __shared__ int s_codes[CODES];
    __shared__ float s_av[CODES];
    __shared__ int s_valid;
    if (tid < 64) {
        int c = codes[(size_t)bv * CODES + tid];
        s_codes[tid] = c;
        float e = (c > 0) ? t[c] : NEG_INF;
        float m = e;
        #pragma unroll
        for (int d = 32; d; d >>= 1) m = fmaxf(m, __shfl_xor(m, d, 64));
        float ex = expf(e - m);
        float s = ex;
        #pragma unroll
        for (int d = 32; d; d >>= 1) s += __shfl_xor(s, d, 64);
        s_av[tid] = ex / s;
        if (tid == 0) s_valid = (m > -1e8f) ? 1 : 0;
    }
    __syncthreads();
    float acc = 0.f;
    #pragma unroll 4
    for (int c = 0; c < CODES; ++c) {
        int node = s_codes[c];
        if (node > 0) acc += s_av[c] * emb[(size_t)node * D + tid];
    }
    int valid = s_valid;
    vemb[(size_t)bv * D + tid] = valid ? acc : 0.f;
    if (tid == 0) vmask[bv] = valid;
}

// ep[b,v] = tanh(vemb[b,v] @ Wp) @ up  (masked -> NEG_INF); one block per (b,v)
__global__ __launch_bounds__(256) void visit_score_kernel(
    const float* __restrict__ vemb, const int* __restrict__ vmask,
    const float* __restrict__ Wp, const float* __restrict__ up,
    float* __restrict__ ep) {
    int bv = blockIdx.x;
    int tid = threadIdx.x;
    __shared__ float s_x[D];
    __shared__ float s_w[4];
    s_x[tid] = vemb[(size_t)bv * D + tid];
    __syncthreads();
    float acc = 0.f;
    #pragma unroll 4
    for (int k = 0; k < D; ++k) acc = fmaf(s_x[k], Wp[(size_t)k * D + tid], acc);
    float y = tanhf(acc) * up[tid];
    #pragma unroll
    for (int d = 32; d; d >>= 1) y += __shfl_xor(y, d, 64);
    if ((tid & 63) == 0) s_w[tid >> 6] = y;
    __syncthreads();
    if (tid == 0) {
        float s = s_w[0] + s_w[1] + s_w[2] + s_w[3];
        ep[bv] = vmask[bv] ? s : NEG_INF;
    }
}

// per-patient: softmax over visits, pemb[b] = sum_v ap[v]*vemb[b,v,:]
__global__ __launch_bounds__(256) void patient_kernel(
    const float* __restrict__ vemb, const float* __restrict__ ep,
    float* __restrict__ pemb) {
    int b = blockIdx.x;
    int tid = threadIdx.x;
    __shared__ float s_ap[VIS];
    __shared__ int s_any;
    if (tid < 64) {
        float e = (tid < VIS) ? ep[b * VIS + tid] : -3e38f;
        float m = e;
        #pragma unroll
        for (int d = 32; d; d >>= 1) m = fmaxf(m, __shfl_xor(m, d, 64));
        float ex = (tid < VIS) ? expf(e - m) : 0.f;
        float s = ex;
        #pragma unroll
        for (int d = 32; d; d >>= 1) s += __shfl_xor(s, d, 64);
        if (tid < VIS) s_ap[tid] = ex / s;
        if (tid == 0) s_any = (m > -1e8f) ? 1 : 0;
    }
    __syncthreads();
    float acc = 0.f;
    for (int v = 0; v < VIS; ++v)
        acc += s_ap[v] * vemb[((size_t)b * VIS + v) * D + tid];
    pemb[b * D + tid] = s_any ? acc : 0.f;
}

// small decoder GEMM: one block per row, thread per output col (chunked)
__global__ __launch_bounds__(256) void gemm_rowcol(
    const float* __restrict__ A, const float* __restrict__ W,
    const float* __restrict__ bias, float* __restrict__ C,
    int M, int N, int K, int act) {
    int row = blockIdx.x;
    int col = blockIdx.y * 256 + threadIdx.x;
    if (col >= N) return;
    const float* a = A + (size_t)row * K;
    float acc = bias ? bias[col] : 0.f;
    #pragma unroll 4
    for (int k = 0; k < K; ++k) acc = fmaf(a[k], W[(size_t)k * N + col], acc);
    if (act == 1) acc = fmaxf(acc, 0.f);
    C[(size_t)row * N + col] = acc;
}

extern "C" void kernel_launch(void* const* d_in, const int* in_sizes, int n_in,
                              void* d_out, int out_size, void* d_ws, size_t ws_size,
                              hipStream_t stream) {
    const int* edge_index   = (const int*)d_in[0];
    const float* edge_weight = (const float*)d_in[1];
    const int* codes        = (const int*)d_in[2];
    const float* node_emb   = (const float*)d_in[3];
    const float* W1 = (const float*)d_in[4];
    const float* b1 = (const float*)d_in[5];
    const float* W2 = (const float*)d_in[6];
    const float* b2 = (const float*)d_in[7];
    const float* Wv = (const float*)d_in[8];
    const float* uv = (const float*)d_in[9];
    const float* Wp = (const float*)d_in[10];
    const float* up = (const float*)d_in[11];
    const float* Wd1 = (const float*)d_in[12];
    const float* bd1 = (const float*)d_in[13];
    const float* Wd2 = (const float*)d_in[14];
    const float* bd2 = (const float*)d_in[15];
    const float* Wd3 = (const float*)d_in[16];
    const float* bd3 = (const float*)d_in[17];

    const int NE = in_sizes[1];          // 3,200,000
    const int NN = in_sizes[3] / D;      // 100,000

    // workspace carve-up (all 256B-aligned)
    char* ws = (char*)d_ws;
    size_t off = 0;
    auto alloc = [&](size_t bytes) -> void* {
        void* p = ws + off;
        off += (bytes + 255) & ~(size_t)255;
        return p;
    };
    float* bufA  = (float*)alloc((size_t)NN * D * 4);       // 102.4 MB
    float* bufB  = (float*)alloc((size_t)NN * D * 4);       // 102.4 MB
    int*   csrc  = (int*)  alloc((size_t)NE * 4);           // 12.8 MB
    float* cw    = (float*)alloc((size_t)NE * 4);           // 12.8 MB
    int*   counts= (int*)  alloc((size_t)NN * 4);
    int*   rp    = (int*)  alloc((size_t)(NN + 1) * 4);
    float* tbuf  = (float*)alloc((size_t)NN * 4);
    float* vemb  = (float*)alloc((size_t)BPAT * VIS * D * 4);
    int*   vmask = (int*)  alloc((size_t)BPAT * VIS * 4);
    float* ep    = (float*)alloc((size_t)BPAT * VIS * 4);
    float* pemb  = (float*)alloc((size_t)BPAT * D * 4);
    float* h1    = (float*)alloc((size_t)BPAT * 512 * 4);
    float* h2    = (float*)alloc((size_t)BPAT * D * 4);
    (void)ws_size; (void)n_in; (void)out_size;

    const int eb = (NE + 255) / 256;
    const int ab = NN / 4;               // one wave per node, 4 waves/block

    // --- CSR build (reused by both agg layers) ---
    hipMemsetAsync(counts, 0, (size_t)NN * 4, stream);
    hist_kernel<<<eb, 256, 0, stream>>>(edge_index, counts, NE);
    scan_kernel<<<1, 1024, 0, stream>>>(counts, rp, NN);
    fill_kernel<<<eb, 256, 0, stream>>>(edge_index, edge_weight, counts, csrc, cw, NE);

    // --- GCN layer 1: h = relu(agg(node_emb) @ W1 + b1) ---
    agg_kernel<<<ab, 256, 0, stream>>>(node_emb, rp, csrc, cw, bufA, NN);
    dim3 gg((NN + 63) / 64, D / 64);
    gemm_bias_act<<<gg, 256, 0, stream>>>(bufA, W1, b1, bufB, NN, D, D, 1);

    // --- GCN layer 2: emb = agg(h) @ W2 + b2 ---
    agg_kernel<<<ab, 256, 0, stream>>>(bufB, rp, csrc, cw, bufA, NN);
    gemm_bias_act<<<gg, 256, 0, stream>>>(bufA, W2, b2, bufB, NN, D, D, 0);   // emb in bufB

    // --- per-node code-attention score: t[n] = tanh(emb @ Wv) @ uv ---
    gemm_bias_act<<<gg, 256, 0, stream>>>(bufB, Wv, nullptr, bufA, NN, D, D, 2);
    dot_uv_kernel<<<ab, 256, 0, stream>>>(bufA, uv, tbuf, NN);

    // --- code attention -> vemb; visit attention -> pemb ---
    code_attn_kernel<<<BPAT * VIS, 256, 0, stream>>>(codes, tbuf, bufB, vemb, vmask);
    visit_score_kernel<<<BPAT * VIS, 256, 0, stream>>>(vemb, vmask, Wp, up, ep);
    patient_kernel<<<BPAT, 256, 0, stream>>>(vemb, ep, pemb);

    // --- decoder MLP ---
    gemm_rowcol<<<dim3(BPAT, 2), 256, 0, stream>>>(pemb, Wd1, bd1, h1, BPAT, 512, D, 1);
    gemm_rowcol<<<dim3(BPAT, 1), 256, 0, stream>>>(h1, Wd2, bd2, h2, BPAT, D, 512, 1);
    gemm_rowcol<<<dim3(BPAT, 4), 256, 0, stream>>>(h2, Wd3, bd3, (float*)d_out, BPAT, 1000, D, 0);
}

// Round 4
// 1207.997 us; speedup vs baseline: 1.9169x; 1.9169x over previous
//
#include <hip/hip_runtime.h>
#include <hip/hip_bf16.h>
#include <math.h>

// DualMAR: 2-layer weighted GCN over 100K nodes / 3.2M edges + code/visit
// attention + MLP decoder.
// R3: bf16 datapath for the GCN (halves gather traffic), bf16 MFMA GEMMs
// (16x16x32, 128x128 tile) for the three [100K,256]x[256,256] matmuls,
// hierarchical scan for CSR build.

#define D 256
#define BPAT 64
#define VIS 50
#define CODES 64
#define NEG_INF -1e9f
#define MPAD 100096   // 782 * 128 (NN=100000 padded to BM=128)

typedef unsigned short ushort_t;
typedef short short8 __attribute__((ext_vector_type(8)));
typedef float f32x4 __attribute__((ext_vector_type(4)));

__device__ __forceinline__ float blo(unsigned u) { return __uint_as_float(u << 16); }
__device__ __forceinline__ float bhi(unsigned u) { return __uint_as_float(u & 0xffff0000u); }
__device__ __forceinline__ float bf2f(ushort_t u) { return __uint_as_float((unsigned)u << 16); }
__device__ __forceinline__ ushort_t f2bfu(float f) {
    __hip_bfloat16 h = __float2bfloat16(f);
    return *reinterpret_cast<ushort_t*>(&h);
}
__device__ __forceinline__ unsigned pack2(float a, float b) {
    return (unsigned)f2bfu(a) | ((unsigned)f2bfu(b) << 16);
}

// ---------------- CSR build ----------------

__global__ void hist_kernel(const int* __restrict__ ei, int* __restrict__ counts, int ne) {
    int e = blockIdx.x * blockDim.x + threadIdx.x;
    if (e < ne) atomicAdd(&counts[ei[(size_t)ne + e]], 1);
}

__global__ __launch_bounds__(1024) void block_sum_kernel(
    const int* __restrict__ counts, int* __restrict__ bsum, int n) {
    __shared__ int wsum[16];
    int tid = threadIdx.x, lane = tid & 63, wid = tid >> 6;
    int i = blockIdx.x * 1024 + tid;
    int v = (i < n) ? counts[i] : 0;
    #pragma unroll
    for (int d = 32; d; d >>= 1) v += __shfl_xor(v, d, 64);
    if (lane == 0) wsum[wid] = v;
    __syncthreads();
    if (tid == 0) {
        int s = 0;
        #pragma unroll
        for (int w = 0; w < 16; ++w) s += wsum[w];
        bsum[blockIdx.x] = s;
    }
}

// single wave: exclusive-scan bsum[0..nb)
__global__ __launch_bounds__(64) void scan_bsum_kernel(int* __restrict__ bsum, int nb) {
    __shared__ int carry;
    int lane = threadIdx.x;
    if (lane == 0) carry = 0;
    __syncthreads();
    for (int base = 0; base < nb; base += 64) {
        int i = base + lane;
        int v = (i < nb) ? bsum[i] : 0;
        int x = v;
        #pragma unroll
        for (int d = 1; d < 64; d <<= 1) {
            int y = __shfl_up(x, (unsigned)d, 64);
            if (lane >= d) x += y;
        }
        int c = carry;
        if (i < nb) bsum[i] = c + x - v;   // exclusive
        __syncthreads();
        if (lane == 63) carry = c + x;
        __syncthreads();
    }
}

__global__ __launch_bounds__(1024) void block_scan_kernel(
    int* __restrict__ counts, const int* __restrict__ bsum,
    int* __restrict__ rp, int n) {
    __shared__ int wsum[16];
    int tid = threadIdx.x, lane = tid & 63, wid = tid >> 6;
    int i = blockIdx.x * 1024 + tid;
    int v = (i < n) ? counts[i] : 0;
    int x = v;
    #pragma unroll
    for (int d = 1; d < 64; d <<= 1) {
        int y = __shfl_up(x, (unsigned)d, 64);
        if (lane >= d) x += y;
    }
    if (lane == 63) wsum[wid] = x;
    __syncthreads();
    int off = bsum[blockIdx.x];
    #pragma unroll
    for (int w = 0; w < 16; ++w) off += (w < wid) ? wsum[w] : 0;
    if (i < n) {
        int incl = off + x;
        rp[i + 1] = incl;
        counts[i] = incl - v;   // exclusive prefix = fill cursor
    }
    if (i == 0) rp[0] = 0;
}

__global__ void fill_kernel(const int* __restrict__ ei, const float* __restrict__ ew,
                            int* __restrict__ cursor, int* __restrict__ csrc,
                            float* __restrict__ cw, int ne) {
    int e = blockIdx.x * blockDim.x + threadIdx.x;
    if (e >= ne) return;
    int d = ei[(size_t)ne + e];
    int pos = atomicAdd(&cursor[d], 1);
    csrc[pos] = ei[e];
    cw[pos] = ew[e];
}

// ---------------- fp32 -> bf16 node table (pad rows zeroed) ----------------
__global__ void cvt_node_kernel(const float* __restrict__ in, ushort_t* __restrict__ out,
                                long n_valid, long n_total) {
    long g = (long)blockIdx.x * blockDim.x + threadIdx.x;
    long ng = n_total >> 2;
    for (long i = g; i < ng; i += (long)gridDim.x * blockDim.x) {
        long e = i << 2;
        uint2 o;
        if (e < n_valid) {
            float4 v = ((const float4*)in)[i];
            o.x = pack2(v.x, v.y);
            o.y = pack2(v.z, v.w);
        } else {
            o.x = 0u; o.y = 0u;
        }
        ((uint2*)out)[i] = o;
    }
}

// ---------------- weight transpose: W[k][n] fp32 -> Wt[n][k] bf16 (256x256) --
__global__ __launch_bounds__(256) void transpose_w_kernel(
    const float* __restrict__ W, ushort_t* __restrict__ Wt) {
    __shared__ float t[32][33];
    int bx = blockIdx.x * 32;   // n base
    int by = blockIdx.y * 32;   // k base
    int lx = threadIdx.x & 31, ly = threadIdx.x >> 5;   // 32 x 8
    #pragma unroll
    for (int i = 0; i < 32; i += 8)
        t[ly + i][lx] = W[(size_t)(by + ly + i) * 256 + bx + lx];
    __syncthreads();
    #pragma unroll
    for (int i = 0; i < 32; i += 8)
        Wt[(size_t)(bx + ly + i) * 256 + by + lx] = f2bfu(t[lx][ly + i]);
}

// ---------------- weighted aggregation over bf16 rows ----------------
// One wave per dst row; 64 lanes x 8B = 512B coalesced row read.
__global__ __launch_bounds__(256) void agg_bf16_kernel(
    const ushort_t* __restrict__ x, const int* __restrict__ rp,
    const int* __restrict__ csrc, const float* __restrict__ cw,
    ushort_t* __restrict__ out, int n) {
    int wv = (int)(((size_t)blockIdx.x * blockDim.x + threadIdx.x) >> 6);
    int lane = threadIdx.x & 63;
    if (wv >= n) return;
    int beg = rp[wv], end = rp[wv + 1];
    float a0 = 0.f, a1 = 0.f, a2 = 0.f, a3 = 0.f;
    int e = beg;
    for (; e + 2 <= end; e += 2) {
        int s0 = csrc[e], s1 = csrc[e + 1];
        float w0 = cw[e], w1 = cw[e + 1];
        uint2 v0 = ((const uint2*)(x + (size_t)s0 * D))[lane];
        uint2 v1 = ((const uint2*)(x + (size_t)s1 * D))[lane];
        a0 += w0 * blo(v0.x) + w1 * blo(v1.x);
        a1 += w0 * bhi(v0.x) + w1 * bhi(v1.x);
        a2 += w0 * blo(v0.y) + w1 * blo(v1.y);
        a3 += w0 * bhi(v0.y) + w1 * bhi(v1.y);
    }
    if (e < end) {
        int s0 = csrc[e];
        float w0 = cw[e];
        uint2 v0 = ((const uint2*)(x + (size_t)s0 * D))[lane];
        a0 += w0 * blo(v0.x); a1 += w0 * bhi(v0.x);
        a2 += w0 * blo(v0.y); a3 += w0 * bhi(v0.y);
    }
    uint2 o;
    o.x = pack2(a0, a1);
    o.y = pack2(a2, a3);
    ((uint2*)(out + (size_t)wv * D))[lane] = o;
}

// ---------------- bf16 MFMA GEMM: out = act(A[MPAD,256] @ W + bias) ----------
// A bf16 row-major, Wt = W^T bf16 (Wt[n][k]). 128x128 tile, BK=32, 4 waves.
// LDS XOR-swizzle: chunk c' = c ^ ((row>>1)&3) keeps ds_read_b128 <=2-way.
// ACT: 0=none 1=relu 2=tanh. OUT_BF16: 1 -> ushort out, 0 -> float out.
template<int ACT, int OUT_BF16>
__global__ __launch_bounds__(256) void mfma_gemm_kernel(
    const ushort_t* __restrict__ A, const ushort_t* __restrict__ Wt,
    const float* __restrict__ bias, void* __restrict__ out) {
    __shared__ __align__(16) ushort_t As[128 * 32];
    __shared__ __align__(16) ushort_t Bs[128 * 32];
    const int tid = threadIdx.x;
    const int lane = tid & 63;
    const int wv = tid >> 6;
    const int wr = wv >> 1, wc = wv & 1;
    const size_t brow = (size_t)blockIdx.x * 128;
    const int bcol = (int)blockIdx.y * 128;

    // two 16B staging chunks per thread: slot s -> row=s>>2, chunk c=s&3
    const int r0 = tid >> 2, c0 = tid & 3;
    const int r1 = (tid + 256) >> 2, c1 = tid & 3;   // s1=tid+256 -> same low bits
    const int cs0 = c0 ^ ((r0 >> 1) & 3);
    const int cs1 = c1 ^ ((r1 >> 1) & 3);
    const ushort_t* gA0 = A + (brow + r0) * 256 + c0 * 8;
    const ushort_t* gA1 = A + (brow + r1) * 256 + c1 * 8;
    const ushort_t* gB0 = Wt + (size_t)(bcol + r0) * 256 + c0 * 8;
    const ushort_t* gB1 = Wt + (size_t)(bcol + r1) * 256 + c1 * 8;
    ushort_t* lA0 = As + r0 * 32 + cs0 * 8;
    ushort_t* lA1 = As + r1 * 32 + cs1 * 8;
    ushort_t* lB0 = Bs + r0 * 32 + cs0 * 8;
    ushort_t* lB1 = Bs + r1 * 32 + cs1 * 8;

    // fragment LDS offsets (ushort units)
    const int g = lane >> 4, rl = lane & 15;
    int aoff[4], boff[4];
    #pragma unroll
    for (int m = 0; m < 4; ++m) {
        int row = wr * 64 + m * 16 + rl;
        aoff[m] = row * 32 + (g ^ ((row >> 1) & 3)) * 8;
    }
    #pragma unroll
    for (int n = 0; n < 4; ++n) {
        int row = wc * 64 + n * 16 + rl;
        boff[n] = row * 32 + (g ^ ((row >> 1) & 3)) * 8;
    }

    f32x4 acc[4][4] = {};

    uint4 va0 = *(const uint4*)gA0;
    uint4 va1 = *(const uint4*)gA1;
    uint4 vb0 = *(const uint4*)gB0;
    uint4 vb1 = *(const uint4*)gB1;

    for (int ks = 0; ks < 8; ++ks) {
        *(uint4*)lA0 = va0; *(uint4*)lA1 = va1;
        *(uint4*)lB0 = vb0; *(uint4*)lB1 = vb1;
        __syncthreads();
        if (ks < 7) {               // prefetch next K-tile during MFMA
            int k0 = (ks + 1) * 32;
            va0 = *(const uint4*)(gA0 + k0);
            va1 = *(const uint4*)(gA1 + k0);
            vb0 = *(const uint4*)(gB0 + k0);
            vb1 = *(const uint4*)(gB1 + k0);
        }
        short8 af[4], bfv[4];
        #pragma unroll
        for (int m = 0; m < 4; ++m) af[m] = *(const short8*)(As + aoff[m]);
        #pragma unroll
        for (int n = 0; n < 4; ++n) bfv[n] = *(const short8*)(Bs + boff[n]);
        #pragma unroll
        for (int m = 0; m < 4; ++m)
            #pragma unroll
            for (int n = 0; n < 4; ++n)
                acc[m][n] = __builtin_amdgcn_mfma_f32_16x16x32_bf16(
                    af[m], bfv[n], acc[m][n], 0, 0, 0);
        __syncthreads();
    }

    // epilogue: D row = (lane>>4)*4 + r, col = lane&15 (m89-verified mapping)
    #pragma unroll
    for (int m = 0; m < 4; ++m) {
        #pragma unroll
        for (int r = 0; r < 4; ++r) {
            size_t row = brow + wr * 64 + m * 16 + (lane >> 4) * 4 + r;
            #pragma unroll
            for (int n = 0; n < 4; ++n) {
                int col = bcol + wc * 64 + n * 16 + rl;
                float v = acc[m][n][r];
                if (bias) v += bias[col];
                if (ACT == 1) v = fmaxf(v, 0.f);
                if (ACT == 2) v = tanhf(v);
                if (OUT_BF16) ((ushort_t*)out)[row * 256 + col] = f2bfu(v);
                else          ((float*)out)[row * 256 + col] = v;
            }
        }
    }
}

// t[n] = dot(tanmat_bf16[n,:], uv_f32) — one wave per row
__global__ __launch_bounds__(256) void dot_uv_bf16_kernel(
    const ushort_t* __restrict__ tanmat, const float* __restrict__ uv,
    float* __restrict__ t, int n) {
    int wv = (int)(((size_t)blockIdx.x * blockDim.x + threadIdx.x) >> 6);
    int lane = threadIdx.x & 63;
    if (wv >= n) return;
    uint2 v = ((const uint2*)(tanmat + (size_t)wv * D))[lane];
    float4 u = ((const float4*)uv)[lane];
    float s = blo(v.x) * u.x + bhi(v.x) * u.y + blo(v.y) * u.z + bhi(v.y) * u.w;
    #pragma unroll
    for (int d = 32; d; d >>= 1) s += __shfl_xor(s, d, 64);
    if (lane == 0) t[wv] = s;
}

// ---------------- code attention: one block per (b,v), emb is bf16 ----------
__global__ __launch_bounds__(256) void code_attn_kernel(
    const int* __restrict__ codes, const float* __restrict__ t,
    const ushort_t* __restrict__ emb, float* __restrict__ vemb,
    int* __restrict__ vmask) {
    int bv = blockIdx.x;
    int tid = threadIdx.x;
    __shared__ int s_codes[CODES];
    __shared__ float s_av[CODES];
    __shared__ int s_valid;
    if (tid < 64) {
        int c = codes[(size_t)bv * CODES + tid];
        s_codes[tid] = c;
        float e = (c > 0) ? t[c] : NEG_INF;
        float m = e;
        #pragma unroll
        for (int d = 32; d; d >>= 1) m = fmaxf(m, __shfl_xor(m, d, 64));
        float ex = expf(e - m);
        float s = ex;
        #pragma unroll
        for (int d = 32; d; d >>= 1) s += __shfl_xor(s, d, 64);
        s_av[tid] = ex / s;
        if (tid == 0) s_valid = (m > -1e8f) ? 1 : 0;
    }
    __syncthreads();
    float acc = 0.f;
    #pragma unroll 4
    for (int c = 0; c < CODES; ++c) {
        int node = s_codes[c];
        if (node > 0) acc += s_av[c] * bf2f(emb[(size_t)node * D + tid]);
    }
    int valid = s_valid;
    vemb[(size_t)bv * D + tid] = valid ? acc : 0.f;
    if (tid == 0) vmask[bv] = valid;
}

// ep[b,v] = tanh(vemb[b,v] @ Wp) @ up (masked); one block per (b,v)
__global__ __launch_bounds__(256) void visit_score_kernel(
    const float* __restrict__ vemb, const int* __restrict__ vmask,
    const float* __restrict__ Wp, const float* __restrict__ up,
    float* __restrict__ ep) {
    int bv = blockIdx.x;
    int tid = threadIdx.x;
    __shared__ float s_x[D];
    __shared__ float s_w[4];
    s_x[tid] = vemb[(size_t)bv * D + tid];
    __syncthreads();
    float acc = 0.f;
    #pragma unroll 4
    for (int k = 0; k < D; ++k) acc = fmaf(s_x[k], Wp[(size_t)k * D + tid], acc);
    float y = tanhf(acc) * up[tid];
    #pragma unroll
    for (int d = 32; d; d >>= 1) y += __shfl_xor(y, d, 64);
    if ((tid & 63) == 0) s_w[tid >> 6] = y;
    __syncthreads();
    if (tid == 0) {
        float s = s_w[0] + s_w[1] + s_w[2] + s_w[3];
        ep[bv] = vmask[bv] ? s : NEG_INF;
    }
}

__global__ __launch_bounds__(256) void patient_kernel(
    const float* __restrict__ vemb, const float* __restrict__ ep,
    float* __restrict__ pemb) {
    int b = blockIdx.x;
    int tid = threadIdx.x;
    __shared__ float s_ap[VIS];
    __shared__ int s_any;
    if (tid < 64) {
        float e = (tid < VIS) ? ep[b * VIS + tid] : -3e38f;
        float m = e;
        #pragma unroll
        for (int d = 32; d; d >>= 1) m = fmaxf(m, __shfl_xor(m, d, 64));
        float ex = (tid < VIS) ? expf(e - m) : 0.f;
        float s = ex;
        #pragma unroll
        for (int d = 32; d; d >>= 1) s += __shfl_xor(s, d, 64);
        if (tid < VIS) s_ap[tid] = ex / s;
        if (tid == 0) s_any = (m > -1e8f) ? 1 : 0;
    }
    __syncthreads();
    float acc = 0.f;
    for (int v = 0; v < VIS; ++v)
        acc += s_ap[v] * vemb[((size_t)b * VIS + v) * D + tid];
    pemb[b * D + tid] = s_any ? acc : 0.f;
}

__global__ __launch_bounds__(256) void gemm_rowcol(
    const float* __restrict__ A, const float* __restrict__ W,
    const float* __restrict__ bias, float* __restrict__ C,
    int M, int N, int K, int act) {
    int row = blockIdx.x;
    int col = blockIdx.y * 256 + threadIdx.x;
    if (col >= N) return;
    const float* a = A + (size_t)row * K;
    float acc = bias ? bias[col] : 0.f;
    #pragma unroll 4
    for (int k = 0; k < K; ++k) acc = fmaf(a[k], W[(size_t)k * N + col], acc);
    if (act == 1) acc = fmaxf(acc, 0.f);
    C[(size_t)row * N + col] = acc;
}

extern "C" void kernel_launch(void* const* d_in, const int* in_sizes, int n_in,
                              void* d_out, int out_size, void* d_ws, size_t ws_size,
                              hipStream_t stream) {
    const int* edge_index    = (const int*)d_in[0];
    const float* edge_weight = (const float*)d_in[1];
    const int* codes         = (const int*)d_in[2];
    const float* node_emb    = (const float*)d_in[3];
    const float* W1 = (const float*)d_in[4];
    const float* b1 = (const float*)d_in[5];
    const float* W2 = (const float*)d_in[6];
    const float* b2 = (const float*)d_in[7];
    const float* Wv = (const float*)d_in[8];
    const float* uv = (const float*)d_in[9];
    const float* Wp = (const float*)d_in[10];
    const float* up = (const float*)d_in[11];
    const float* Wd1 = (const float*)d_in[12];
    const float* bd1 = (const float*)d_in[13];
    const float* Wd2 = (const float*)d_in[14];
    const float* bd2 = (const float*)d_in[15];
    const float* Wd3 = (const float*)d_in[16];
    const float* bd3 = (const float*)d_in[17];

    const int NE = in_sizes[1];          // 3,200,000
    const int NN = in_sizes[3] / D;      // 100,000

    char* ws = (char*)d_ws;
    size_t off = 0;
    auto alloc = [&](size_t bytes) -> void* {
        void* p = ws + off;
        off += (bytes + 255) & ~(size_t)255;
        return p;
    };
    // bf16 buffers (MPAD rows; pad rows never read by downstream consumers)
    ushort_t* nbf  = (ushort_t*)alloc((size_t)MPAD * D * 2);  // node table / reused as hbuf
    ushort_t* aggb = (ushort_t*)alloc((size_t)MPAD * D * 2);  // agg out / reused as tanbuf
    ushort_t* embB = (ushort_t*)alloc((size_t)MPAD * D * 2);  // emb (bf16)
    int*   csrc   = (int*)  alloc((size_t)NE * 4);
    float* cw     = (float*)alloc((size_t)NE * 4);
    int*   counts = (int*)  alloc((size_t)NN * 4);
    int*   rp     = (int*)  alloc((size_t)(NN + 1) * 4);
    int*   bsum   = (int*)  alloc(1024 * 4);
    ushort_t* W1t = (ushort_t*)alloc(256 * 256 * 2);
    ushort_t* W2t = (ushort_t*)alloc(256 * 256 * 2);
    ushort_t* Wvt = (ushort_t*)alloc(256 * 256 * 2);
    float* tbuf  = (float*)alloc((size_t)NN * 4);
    float* vemb  = (float*)alloc((size_t)BPAT * VIS * D * 4);
    int*   vmask = (int*)  alloc((size_t)BPAT * VIS * 4);
    float* ep    = (float*)alloc((size_t)BPAT * VIS * 4);
    float* pemb  = (float*)alloc((size_t)BPAT * D * 4);
    float* h1    = (float*)alloc((size_t)BPAT * 512 * 4);
    float* h2    = (float*)alloc((size_t)BPAT * D * 4);
    (void)ws_size; (void)n_in; (void)out_size;

    const int eb = (NE + 255) / 256;
    const int ab = NN / 4;                    // one wave/row, 4 waves/block
    const int nb = (NN + 1023) / 1024;        // 98 scan blocks

    // --- CSR build ---
    hipMemsetAsync(counts, 0, (size_t)NN * 4, stream);
    hist_kernel<<<eb, 256, 0, stream>>>(edge_index, counts, NE);
    block_sum_kernel<<<nb, 1024, 0, stream>>>(counts, bsum, NN);
    scan_bsum_kernel<<<1, 64, 0, stream>>>(bsum, nb);
    block_scan_kernel<<<nb, 1024, 0, stream>>>(counts, bsum, rp, NN);
    fill_kernel<<<eb, 256, 0, stream>>>(edge_index, edge_weight, counts, csrc, cw, NE);

    // --- bf16 conversions (node table + weight transposes) ---
    cvt_node_kernel<<<2048, 256, 0, stream>>>(node_emb, nbf, (long)NN * D, (long)MPAD * D);
    dim3 tg(8, 8);
    transpose_w_kernel<<<tg, 256, 0, stream>>>(W1, W1t);
    transpose_w_kernel<<<tg, 256, 0, stream>>>(W2, W2t);
    transpose_w_kernel<<<tg, 256, 0, stream>>>(Wv, Wvt);

    dim3 gg(MPAD / 128, 2);

    // --- GCN layer 1: h = relu(agg(x) @ W1 + b1) ---
    agg_bf16_kernel<<<ab, 256, 0, stream>>>(nbf, rp, csrc, cw, aggb, NN);
    mfma_gemm_kernel<1, 1><<<gg, 256, 0, stream>>>(aggb, W1t, b1, nbf);   // hbuf = nbf

    // --- GCN layer 2: emb = agg(h) @ W2 + b2 ---
    agg_bf16_kernel<<<ab, 256, 0, stream>>>(nbf, rp, csrc, cw, aggb, NN);
    mfma_gemm_kernel<0, 1><<<gg, 256, 0, stream>>>(aggb, W2t, b2, embB);

    // --- per-node code score: t = tanh(emb @ Wv) @ uv ---
    mfma_gemm_kernel<2, 1><<<gg, 256, 0, stream>>>(embB, Wvt, nullptr, aggb); // tanbuf = aggb
    dot_uv_bf16_kernel<<<ab, 256, 0, stream>>>(aggb, uv, tbuf, NN);

    // --- attention + decoder ---
    code_attn_kernel<<<BPAT * VIS, 256, 0, stream>>>(codes, tbuf, embB, vemb, vmask);
    visit_score_kernel<<<BPAT * VIS, 256, 0, stream>>>(vemb, vmask, Wp, up, ep);
    patient_kernel<<<BPAT, 256, 0, stream>>>(vemb, ep, pemb);
    gemm_rowcol<<<dim3(BPAT, 2), 256, 0, stream>>>(pemb, Wd1, bd1, h1, BPAT, 512, D, 1);
    gemm_rowcol<<<dim3(BPAT, 1), 256, 0, stream>>>(h1, Wd2, bd2, h2, BPAT, D, 512, 1);
    gemm_rowcol<<<dim3(BPAT, 4), 256, 0, stream>>>(h2, Wd3, bd3, (float*)d_out, BPAT, 1000, D, 0);
}

// Round 5
// 1103.545 us; speedup vs baseline: 2.0983x; 1.0947x over previous
//
#include <hip/hip_runtime.h>
#include <hip/hip_bf16.h>
#include <math.h>

// DualMAR: 2-layer weighted GCN over 100K nodes / 3.2M edges + code/visit
// attention + MLP decoder.
// R4: interleaved (src,w) edge pairs (halves fill scatter-line traffic),
// half-wave uint4 agg gather (halves vmem instr count, 8-edge unroll),
// BN=256 MFMA GEMM (A read once), fused tanh-dot epilogue replaces
// dot_uv and visit_score kernels.

#define D 256
#define BPAT 64
#define VIS 50
#define CODES 64
#define NEG_INF -1e9f
#define MPAD 100096   // 782 * 128 (NN=100000 padded to BM=128)

typedef unsigned short ushort_t;
typedef short short8 __attribute__((ext_vector_type(8)));
typedef float f32x4 __attribute__((ext_vector_type(4)));

__device__ __forceinline__ float blo(unsigned u) { return __uint_as_float(u << 16); }
__device__ __forceinline__ float bhi(unsigned u) { return __uint_as_float(u & 0xffff0000u); }
__device__ __forceinline__ float bf2f(ushort_t u) { return __uint_as_float((unsigned)u << 16); }
__device__ __forceinline__ ushort_t f2bfu(float f) {
    __hip_bfloat16 h = __float2bfloat16(f);
    return *reinterpret_cast<ushort_t*>(&h);
}
__device__ __forceinline__ unsigned pack2(float a, float b) {
    return (unsigned)f2bfu(a) | ((unsigned)f2bfu(b) << 16);
}

// ---------------- CSR build ----------------

__global__ void hist_kernel(const int* __restrict__ ei, int* __restrict__ counts, int ne) {
    int e = blockIdx.x * blockDim.x + threadIdx.x;
    if (e < ne) atomicAdd(&counts[ei[(size_t)ne + e]], 1);
}

__global__ __launch_bounds__(1024) void block_sum_kernel(
    const int* __restrict__ counts, int* __restrict__ bsum, int n) {
    __shared__ int wsum[16];
    int tid = threadIdx.x, lane = tid & 63, wid = tid >> 6;
    int i = blockIdx.x * 1024 + tid;
    int v = (i < n) ? counts[i] : 0;
    #pragma unroll
    for (int d = 32; d; d >>= 1) v += __shfl_xor(v, d, 64);
    if (lane == 0) wsum[wid] = v;
    __syncthreads();
    if (tid == 0) {
        int s = 0;
        #pragma unroll
        for (int w = 0; w < 16; ++w) s += wsum[w];
        bsum[blockIdx.x] = s;
    }
}

__global__ __launch_bounds__(64) void scan_bsum_kernel(int* __restrict__ bsum, int nb) {
    __shared__ int carry;
    int lane = threadIdx.x;
    if (lane == 0) carry = 0;
    __syncthreads();
    for (int base = 0; base < nb; base += 64) {
        int i = base + lane;
        int v = (i < nb) ? bsum[i] : 0;
        int x = v;
        #pragma unroll
        for (int d = 1; d < 64; d <<= 1) {
            int y = __shfl_up(x, (unsigned)d, 64);
            if (lane >= d) x += y;
        }
        int c = carry;
        if (i < nb) bsum[i] = c + x - v;   // exclusive
        __syncthreads();
        if (lane == 63) carry = c + x;
        __syncthreads();
    }
}

__global__ __launch_bounds__(1024) void block_scan_kernel(
    int* __restrict__ counts, const int* __restrict__ bsum,
    int* __restrict__ rp, int n) {
    __shared__ int wsum[16];
    int tid = threadIdx.x, lane = tid & 63, wid = tid >> 6;
    int i = blockIdx.x * 1024 + tid;
    int v = (i < n) ? counts[i] : 0;
    int x = v;
    #pragma unroll
    for (int d = 1; d < 64; d <<= 1) {
        int y = __shfl_up(x, (unsigned)d, 64);
        if (lane >= d) x += y;
    }
    if (lane == 63) wsum[wid] = x;
    __syncthreads();
    int off = bsum[blockIdx.x];
    #pragma unroll
    for (int w = 0; w < 16; ++w) off += (w < wid) ? wsum[w] : 0;
    if (i < n) {
        int incl = off + x;
        rp[i + 1] = incl;
        counts[i] = incl - v;   // exclusive prefix = fill cursor
    }
    if (i == 0) rp[0] = 0;
}

// interleaved (src, weight-bits) pair: one 8B scatter per edge
__global__ void fill_kernel(const int* __restrict__ ei, const float* __restrict__ ew,
                            int* __restrict__ cursor, uint2* __restrict__ ep, int ne) {
    int e = blockIdx.x * blockDim.x + threadIdx.x;
    if (e >= ne) return;
    int d = ei[(size_t)ne + e];
    int pos = atomicAdd(&cursor[d], 1);
    ep[pos] = make_uint2((unsigned)ei[e], __float_as_uint(ew[e]));
}

// ---------------- fp32 -> bf16 node table (pad rows zeroed) ----------------
__global__ void cvt_node_kernel(const float* __restrict__ in, ushort_t* __restrict__ out,
                                long n_valid, long n_total) {
    long g = (long)blockIdx.x * blockDim.x + threadIdx.x;
    long ng = n_total >> 2;
    for (long i = g; i < ng; i += (long)gridDim.x * blockDim.x) {
        long e = i << 2;
        uint2 o;
        if (e < n_valid) {
            float4 v = ((const float4*)in)[i];
            o.x = pack2(v.x, v.y);
            o.y = pack2(v.z, v.w);
        } else {
            o.x = 0u; o.y = 0u;
        }
        ((uint2*)out)[i] = o;
    }
}

// ---------------- weight transpose: W[k][n] fp32 -> Wt[n][k] bf16 (256x256) --
__global__ __launch_bounds__(256) void transpose_w_kernel(
    const float* __restrict__ W, ushort_t* __restrict__ Wt) {
    __shared__ float t[32][33];
    int bx = blockIdx.x * 32;   // n base
    int by = blockIdx.y * 32;   // k base
    int lx = threadIdx.x & 31, ly = threadIdx.x >> 5;   // 32 x 8
    #pragma unroll
    for (int i = 0; i < 32; i += 8)
        t[ly + i][lx] = W[(size_t)(by + ly + i) * 256 + bx + lx];
    __syncthreads();
    #pragma unroll
    for (int i = 0; i < 32; i += 8)
        Wt[(size_t)(bx + ly + i) * 256 + by + lx] = f2bfu(t[lx][ly + i]);
}

// ---------------- weighted aggregation over bf16 rows ----------------
// One wave per dst row, split into two 32-lane halves: each half gathers a
// DIFFERENT edge with 16B/lane uint4 loads (32 lanes x 16B = 512B row).
// 8-edge unrolled main loop -> 4 uint4 gathers in flight per wave.
__device__ __forceinline__ void acc8(float* a, uint4 v, float w) {
    a[0] += w * blo(v.x); a[1] += w * bhi(v.x);
    a[2] += w * blo(v.y); a[3] += w * bhi(v.y);
    a[4] += w * blo(v.z); a[5] += w * bhi(v.z);
    a[6] += w * blo(v.w); a[7] += w * bhi(v.w);
}

__global__ __launch_bounds__(256) void agg_bf16_kernel(
    const ushort_t* __restrict__ x, const int* __restrict__ rp,
    const uint2* __restrict__ ep, ushort_t* __restrict__ out, int n) {
    int wv = (int)(((size_t)blockIdx.x * blockDim.x + threadIdx.x) >> 6);
    int lane = threadIdx.x & 63;
    if (wv >= n) return;
    int half = lane >> 5;
    int l32 = lane & 31;
    int beg = rp[wv], end = rp[wv + 1];
    float a[8] = {};
    int e = beg;
    for (; e + 8 <= end; e += 8) {
        uint2 p0 = ep[e + half];
        uint2 p1 = ep[e + 2 + half];
        uint2 p2 = ep[e + 4 + half];
        uint2 p3 = ep[e + 6 + half];
        uint4 v0 = ((const uint4*)(x + (size_t)p0.x * D))[l32];
        uint4 v1 = ((const uint4*)(x + (size_t)p1.x * D))[l32];
        uint4 v2 = ((const uint4*)(x + (size_t)p2.x * D))[l32];
        uint4 v3 = ((const uint4*)(x + (size_t)p3.x * D))[l32];
        acc8(a, v0, __uint_as_float(p0.y));
        acc8(a, v1, __uint_as_float(p1.y));
        acc8(a, v2, __uint_as_float(p2.y));
        acc8(a, v3, __uint_as_float(p3.y));
    }
    for (; e + 2 <= end; e += 2) {
        uint2 p0 = ep[e + half];
        uint4 v0 = ((const uint4*)(x + (size_t)p0.x * D))[l32];
        acc8(a, v0, __uint_as_float(p0.y));
    }
    if (e < end) {   // odd tail: both halves read the same row, upper weight 0
        uint2 p0 = ep[e];
        uint4 v0 = ((const uint4*)(x + (size_t)p0.x * D))[l32];
        acc8(a, v0, half ? 0.f : __uint_as_float(p0.y));
    }
    #pragma unroll
    for (int j = 0; j < 8; ++j) a[j] += __shfl_xor(a[j], 32, 64);
    if (half == 0) {
        uint4 o;
        o.x = pack2(a[0], a[1]); o.y = pack2(a[2], a[3]);
        o.z = pack2(a[4], a[5]); o.w = pack2(a[6], a[7]);
        ((uint4*)(out + (size_t)wv * D))[l32] = o;
    }
}

// ---------------- bf16 MFMA GEMM: 128x256 tile, BK=32, 8 waves (512 thr) ----
// A bf16 row-major [*,256]; Wt = W^T bf16. LDS XOR-swizzle c^=((row>>1)&3).
// MODE 0: relu(A@W+bias) -> bf16 out
// MODE 1: A@W+bias       -> bf16 out
// MODE 2: tout[row] = sum_col tanh((A@W)[row,col]) * u[col]  (no out store)
template<int MODE>
__global__ __launch_bounds__(512) void mfma_gemm_kernel(
    const ushort_t* __restrict__ A, const ushort_t* __restrict__ Wt,
    const float* __restrict__ bias, ushort_t* __restrict__ out,
    const float* __restrict__ u, float* __restrict__ tout, int mvalid) {
    __shared__ __align__(16) ushort_t As[128 * 32];
    __shared__ __align__(16) ushort_t Bs[256 * 32];
    __shared__ float s_t[128];
    const int tid = threadIdx.x;
    const int lane = tid & 63;
    const int wv = tid >> 6;           // 0..7
    const int wr = wv >> 2, wc = wv & 3;
    const size_t brow = (size_t)blockIdx.x * 128;

    // staging: A = 512 16B-chunks (1/thread), B = 1024 chunks (2/thread)
    const int ra = tid >> 2, ca = tid & 3;
    const int rb1 = ra + 128;
    const int csa = ca ^ ((ra >> 1) & 3);          // note: same for rb1 (128%4==0... (ra+128)>>1 = ra>>1 + 64, &3 unchanged)
    const ushort_t* gA  = A  + (brow + ra) * 256 + ca * 8;
    const ushort_t* gB0 = Wt + (size_t)ra  * 256 + ca * 8;
    const ushort_t* gB1 = Wt + (size_t)rb1 * 256 + ca * 8;
    ushort_t* lA  = As + ra * 32 + csa * 8;
    ushort_t* lB0 = Bs + ra * 32 + csa * 8;
    ushort_t* lB1 = Bs + rb1 * 32 + csa * 8;

    const int g = lane >> 4, rl = lane & 15;
    int aoff[4], boff[4];
    #pragma unroll
    for (int m = 0; m < 4; ++m) {
        int row = wr * 64 + m * 16 + rl;
        aoff[m] = row * 32 + (g ^ ((row >> 1) & 3)) * 8;
    }
    #pragma unroll
    for (int n = 0; n < 4; ++n) {
        int row = wc * 64 + n * 16 + rl;
        boff[n] = row * 32 + (g ^ ((row >> 1) & 3)) * 8;
    }

    if (MODE == 2 && tid < 128) s_t[tid] = 0.f;

    f32x4 acc[4][4] = {};
    uint4 va  = *(const uint4*)gA;
    uint4 vb0 = *(const uint4*)gB0;
    uint4 vb1 = *(const uint4*)gB1;

    for (int ks = 0; ks < 8; ++ks) {
        *(uint4*)lA = va; *(uint4*)lB0 = vb0; *(uint4*)lB1 = vb1;
        __syncthreads();
        if (ks < 7) {
            int k0 = (ks + 1) * 32;
            va  = *(const uint4*)(gA + k0);
            vb0 = *(const uint4*)(gB0 + k0);
            vb1 = *(const uint4*)(gB1 + k0);
        }
        short8 af[4], bfv[4];
        #pragma unroll
        for (int m = 0; m < 4; ++m) af[m] = *(const short8*)(As + aoff[m]);
        #pragma unroll
        for (int n = 0; n < 4; ++n) bfv[n] = *(const short8*)(Bs + boff[n]);
        #pragma unroll
        for (int m = 0; m < 4; ++m)
            #pragma unroll
            for (int n = 0; n < 4; ++n)
                acc[m][n] = __builtin_amdgcn_mfma_f32_16x16x32_bf16(
                    af[m], bfv[n], acc[m][n], 0, 0, 0);
        __syncthreads();
    }

    if (MODE == 2) {
        float uvv[4];
        #pragma unroll
        for (int n = 0; n < 4; ++n) uvv[n] = u[wc * 64 + n * 16 + rl];
        #pragma unroll
        for (int m = 0; m < 4; ++m) {
            #pragma unroll
            for (int r = 0; r < 4; ++r) {
                float v = 0.f;
                #pragma unroll
                for (int n = 0; n < 4; ++n) v += tanhf(acc[m][n][r]) * uvv[n];
                v += __shfl_xor(v, 1, 64);
                v += __shfl_xor(v, 2, 64);
                v += __shfl_xor(v, 4, 64);
                v += __shfl_xor(v, 8, 64);
                if (rl == 0) atomicAdd(&s_t[wr * 64 + m * 16 + g * 4 + r], v);
            }
        }
        __syncthreads();
        if (tid < 128 && brow + tid < (size_t)mvalid) tout[brow + tid] = s_t[tid];
    } else {
        #pragma unroll
        for (int m = 0; m < 4; ++m) {
            #pragma unroll
            for (int r = 0; r < 4; ++r) {
                size_t row = brow + wr * 64 + m * 16 + g * 4 + r;
                #pragma unroll
                for (int n = 0; n < 4; ++n) {
                    int col = wc * 64 + n * 16 + rl;
                    float v = acc[m][n][r] + bias[col];
                    if (MODE == 0) v = fmaxf(v, 0.f);
                    out[row * 256 + col] = f2bfu(v);
                }
            }
        }
    }
}

// ---------------- code attention: one block per (b,v), emb bf16 -> vemb bf16
__global__ __launch_bounds__(256) void code_attn_kernel(
    const int* __restrict__ codes, const float* __restrict__ t,
    const ushort_t* __restrict__ emb, ushort_t* __restrict__ vembB,
    int* __restrict__ vmask) {
    int bv = blockIdx.x;
    int tid = threadIdx.x;
    __shared__ int s_codes[CODES];
    __shared__ float s_av[CODES];
    __shared__ int s_valid;
    if (tid < 64) {
        int c = codes[(size_t)bv * CODES + tid];
        s_codes[tid] = c;
        float e = (c > 0) ? t[c] : NEG_INF;
        float m = e;
        #pragma unroll
        for (int d = 32; d; d >>= 1) m = fmaxf(m, __shfl_xor(m, d, 64));
        float ex = expf(e - m);
        float s = ex;
        #pragma unroll
        for (int d = 32; d; d >>= 1) s += __shfl_xor(s, d, 64);
        s_av[tid] = ex / s;
        if (tid == 0) s_valid = (m > -1e8f) ? 1 : 0;
    }
    __syncthreads();
    float acc = 0.f;
    #pragma unroll 4
    for (int c = 0; c < CODES; ++c) {
        int node = s_codes[c];
        if (node > 0) acc += s_av[c] * bf2f(emb[(size_t)node * D + tid]);
    }
    int valid = s_valid;
    vembB[(size_t)bv * D + tid] = f2bfu(valid ? acc : 0.f);
    if (tid == 0) vmask[bv] = valid;
}

// per-patient: masked softmax over visit scores, pemb = sum ap * vemb
__global__ __launch_bounds__(256) void patient_kernel(
    const ushort_t* __restrict__ vembB, const float* __restrict__ epr,
    const int* __restrict__ vmask, float* __restrict__ pemb) {
    int b = blockIdx.x;
    int tid = threadIdx.x;
    __shared__ float s_ap[VIS];
    __shared__ int s_any;
    if (tid < 64) {
        float e = -3e38f;
        if (tid < VIS) e = vmask[b * VIS + tid] ? epr[b * VIS + tid] : NEG_INF;
        float m = e;
        #pragma unroll
        for (int d = 32; d; d >>= 1) m = fmaxf(m, __shfl_xor(m, d, 64));
        float ex = (tid < VIS) ? expf(e - m) : 0.f;
        float s = ex;
        #pragma unroll
        for (int d = 32; d; d >>= 1) s += __shfl_xor(s, d, 64);
        if (tid < VIS) s_ap[tid] = ex / s;
        if (tid == 0) s_any = (m > -1e8f) ? 1 : 0;
    }
    __syncthreads();
    float acc = 0.f;
    for (int v = 0; v < VIS; ++v)
        acc += s_ap[v] * bf2f(vembB[((size_t)b * VIS + v) * D + tid]);
    pemb[b * D + tid] = s_any ? acc : 0.f;
}

__global__ __launch_bounds__(256) void gemm_rowcol(
    const float* __restrict__ A, const float* __restrict__ W,
    const float* __restrict__ bias, float* __restrict__ C,
    int M, int N, int K, int act) {
    int row = blockIdx.x;
    int col = blockIdx.y * 256 + threadIdx.x;
    if (col >= N) return;
    const float* a = A + (size_t)row * K;
    float acc = bias ? bias[col] : 0.f;
    #pragma unroll 4
    for (int k = 0; k < K; ++k) acc = fmaf(a[k], W[(size_t)k * N + col], acc);
    if (act == 1) acc = fmaxf(acc, 0.f);
    C[(size_t)row * N + col] = acc;
}

extern "C" void kernel_launch(void* const* d_in, const int* in_sizes, int n_in,
                              void* d_out, int out_size, void* d_ws, size_t ws_size,
                              hipStream_t stream) {
    const int* edge_index    = (const int*)d_in[0];
    const float* edge_weight = (const float*)d_in[1];
    const int* codes         = (const int*)d_in[2];
    const float* node_emb    = (const float*)d_in[3];
    const float* W1 = (const float*)d_in[4];
    const float* b1 = (const float*)d_in[5];
    const float* W2 = (const float*)d_in[6];
    const float* b2 = (const float*)d_in[7];
    const float* Wv = (const float*)d_in[8];
    const float* uv = (const float*)d_in[9];
    const float* Wp = (const float*)d_in[10];
    const float* up = (const float*)d_in[11];
    const float* Wd1 = (const float*)d_in[12];
    const float* bd1 = (const float*)d_in[13];
    const float* Wd2 = (const float*)d_in[14];
    const float* bd2 = (const float*)d_in[15];
    const float* Wd3 = (const float*)d_in[16];
    const float* bd3 = (const float*)d_in[17];

    const int NE = in_sizes[1];          // 3,200,000
    const int NN = in_sizes[3] / D;      // 100,000

    char* ws = (char*)d_ws;
    size_t off = 0;
    auto alloc = [&](size_t bytes) -> void* {
        void* p = ws + off;
        off += (bytes + 255) & ~(size_t)255;
        return p;
    };
    ushort_t* nbf  = (ushort_t*)alloc((size_t)MPAD * D * 2);  // node table / h
    ushort_t* aggb = (ushort_t*)alloc((size_t)MPAD * D * 2);  // agg out
    ushort_t* embB = (ushort_t*)alloc((size_t)MPAD * D * 2);  // emb (bf16)
    uint2* epair  = (uint2*)alloc((size_t)NE * 8);            // (src, w) pairs
    int*   counts = (int*)  alloc((size_t)NN * 4);
    int*   rp     = (int*)  alloc((size_t)(NN + 1) * 4);
    int*   bsum   = (int*)  alloc(1024 * 4);
    ushort_t* W1t = (ushort_t*)alloc(256 * 256 * 2);
    ushort_t* W2t = (ushort_t*)alloc(256 * 256 * 2);
    ushort_t* Wvt = (ushort_t*)alloc(256 * 256 * 2);
    ushort_t* Wpt = (ushort_t*)alloc(256 * 256 * 2);
    float* tbuf  = (float*)alloc((size_t)NN * 4);
    ushort_t* vembB = (ushort_t*)alloc((size_t)BPAT * VIS * D * 2);
    int*   vmask = (int*)  alloc((size_t)BPAT * VIS * 4);
    float* epr   = (float*)alloc((size_t)BPAT * VIS * 4);
    float* pemb  = (float*)alloc((size_t)BPAT * D * 4);
    float* h1    = (float*)alloc((size_t)BPAT * 512 * 4);
    float* h2    = (float*)alloc((size_t)BPAT * D * 4);
    (void)ws_size; (void)n_in; (void)out_size;

    const int eb = (NE + 255) / 256;
    const int ab = NN / 4;                    // one wave/row, 4 waves/block
    const int nb = (NN + 1023) / 1024;

    // --- CSR build ---
    hipMemsetAsync(counts, 0, (size_t)NN * 4, stream);
    hist_kernel<<<eb, 256, 0, stream>>>(edge_index, counts, NE);
    block_sum_kernel<<<nb, 1024, 0, stream>>>(counts, bsum, NN);
    scan_bsum_kernel<<<1, 64, 0, stream>>>(bsum, nb);
    block_scan_kernel<<<nb, 1024, 0, stream>>>(counts, bsum, rp, NN);
    fill_kernel<<<eb, 256, 0, stream>>>(edge_index, edge_weight, counts, epair, NE);

    // --- bf16 conversions ---
    cvt_node_kernel<<<2048, 256, 0, stream>>>(node_emb, nbf, (long)NN * D, (long)MPAD * D);
    dim3 tg(8, 8);
    transpose_w_kernel<<<tg, 256, 0, stream>>>(W1, W1t);
    transpose_w_kernel<<<tg, 256, 0, stream>>>(W2, W2t);
    transpose_w_kernel<<<tg, 256, 0, stream>>>(Wv, Wvt);
    transpose_w_kernel<<<tg, 256, 0, stream>>>(Wp, Wpt);

    // --- GCN layer 1: h = relu(agg(x) @ W1 + b1) ---
    agg_bf16_kernel<<<ab, 256, 0, stream>>>(nbf, rp, epair, aggb, NN);
    mfma_gemm_kernel<0><<<MPAD / 128, 512, 0, stream>>>(
        aggb, W1t, b1, nbf, nullptr, nullptr, 0);

    // --- GCN layer 2: emb = agg(h) @ W2 + b2 ---
    agg_bf16_kernel<<<ab, 256, 0, stream>>>(nbf, rp, epair, aggb, NN);
    mfma_gemm_kernel<1><<<MPAD / 128, 512, 0, stream>>>(
        aggb, W2t, b2, embB, nullptr, nullptr, 0);

    // --- fused per-node code score: t = tanh(emb @ Wv) @ uv ---
    mfma_gemm_kernel<2><<<MPAD / 128, 512, 0, stream>>>(
        embB, Wvt, nullptr, nullptr, uv, tbuf, NN);

    // --- code attention -> vemb (bf16) ---
    code_attn_kernel<<<BPAT * VIS, 256, 0, stream>>>(codes, tbuf, embB, vembB, vmask);

    // --- fused visit score: ep = tanh(vemb @ Wp) @ up  (3200 = 25*128 rows) ---
    mfma_gemm_kernel<2><<<BPAT * VIS / 128, 512, 0, stream>>>(
        vembB, Wpt, nullptr, nullptr, up, epr, BPAT * VIS);

    // --- patient attention + decoder ---
    patient_kernel<<<BPAT, 256, 0, stream>>>(vembB, epr, vmask, pemb);
    gemm_rowcol<<<dim3(BPAT, 2), 256, 0, stream>>>(pemb, Wd1, bd1, h1, BPAT, 512, D, 1);
    gemm_rowcol<<<dim3(BPAT, 1), 256, 0, stream>>>(h1, Wd2, bd2, h2, BPAT, D, 512, 1);
    gemm_rowcol<<<dim3(BPAT, 4), 256, 0, stream>>>(h2, Wd3, bd3, (float*)d_out, BPAT, 1000, D, 0);
}